// Round 6
// baseline (202.844 us; speedup 1.0000x reference)
//
#include <hip/hip_runtime.h>
#include <cstdint>
#include <cstddef>

// Problem dims (fixed by the reference setup_inputs):
#define B_DIM   8192
#define IN_DIM  1024
#define OUT_DIM 4096
#define KT2     (IN_DIM / 64)    // 16 panels (of K=64) per 32-row tile

typedef __attribute__((ext_vector_type(8)))  int   i32x8;   // fp8 MFMA A/B frag (32 B)
typedef __attribute__((ext_vector_type(4)))  int   i32x4;
typedef __attribute__((ext_vector_type(16))) float f32x16;  // 32x32 MFMA accumulator

// async global->LDS DMA, 16B per lane. LDS dest is wave-uniform base + lane*16.
__device__ __forceinline__ void async_copy16(const void* gptr, void* ldsptr) {
    __builtin_amdgcn_global_load_lds(
        (__attribute__((address_space(1))) void*)gptr,
        (__attribute__((address_space(3))) void*)ldsptr,
        16, 0, 0);
}

// pack 4 fp32 -> 4 OCP e4m3 bytes (little-endian k order)
__device__ __forceinline__ int pack4_fp8(float a, float b, float c, float d) {
    int pk = __builtin_amdgcn_cvt_pk_fp8_f32(a, b, 0, false);   // bytes 0-1
    pk = __builtin_amdgcn_cvt_pk_fp8_f32(c, d, pk, true);       // bytes 2-3
    return pk;
}

// fp8 panel: 32 rows x 64 k = 2048 B. Lane l owns row m=l&31, k=(l>>5)*32+[0,32).
// Stored pre-split into the two 1KB halves: half h at panel + h*1024 + l*16.
// => staging DMA, LDS frag reads AND direct global frag loads are all the
// lane-linear base + lane*16 pattern (conflict-free, fully coalesced).

// ---------------------------------------------------------------------------
// Kernel 1: x (fp32, B x IN row-major) -> fp8 A panels + xsq (exact fp32).
// Blocks 0..15 also zero wsq (stream order precedes tile_w's atomics).
// ---------------------------------------------------------------------------
__global__ __launch_bounds__(256) void tile_x_kernel(
    const float* __restrict__ x, unsigned char* __restrict__ At,
    float* __restrict__ xsq, float* __restrict__ wsq)
{
    const int t = threadIdx.x;
    const int w = t >> 6;
    const int l = t & 63;
    const int mt = blockIdx.x;            // 0..255
    const int m  = mt * 32 + (l & 31);

    float s = 0.0f;
    #pragma unroll
    for (int c = 0; c < 4; ++c) {
        const int kt2 = c * 4 + w;
        const float* src = x + (size_t)m * IN_DIM + kt2 * 64 + (l >> 5) * 32;
        i32x4 lo, hi;
        #pragma unroll
        for (int j = 0; j < 4; ++j) {
            float4 v = ((const float4*)src)[j];
            s += v.x*v.x + v.y*v.y + v.z*v.z + v.w*v.w;
            lo[j] = pack4_fp8(v.x, v.y, v.z, v.w);
        }
        #pragma unroll
        for (int j = 0; j < 4; ++j) {
            float4 v = ((const float4*)src)[4 + j];
            s += v.x*v.x + v.y*v.y + v.z*v.z + v.w*v.w;
            hi[j] = pack4_fp8(v.x, v.y, v.z, v.w);
        }
        unsigned char* pan = At + ((size_t)mt * KT2 + kt2) * 2048;
        *(i32x4*)(pan + l * 16)        = lo;
        *(i32x4*)(pan + 1024 + l * 16) = hi;
    }
    s += __shfl_down(s, 32, 64);          // lanes l, l+32 hold the same row
    __shared__ float red[4][32];
    if (l < 32) red[w][l] = s;
    __syncthreads();
    if (t < 32) xsq[mt * 32 + t] = red[0][t] + red[1][t] + red[2][t] + red[3][t];

    if (blockIdx.x < OUT_DIM / 256) wsq[blockIdx.x * 256 + t] = 0.0f;
}

// ---------------------------------------------------------------------------
// Kernel 2: W (fp32, IN x OUT row-major) -> fp8 B panels (transpose via LDS)
// + wsq partials (exact fp32, atomicAdd). grid (OUT/32, 4).
// ---------------------------------------------------------------------------
__global__ __launch_bounds__(256) void tile_w_kernel(
    const float* __restrict__ wgt, unsigned char* __restrict__ Bt,
    float* __restrict__ wsq)
{
    __shared__ float tile[256 * 33];      // [k][n], pad 33
    const int t  = threadIdx.x;
    const int w  = t >> 6;
    const int l  = t & 63;
    const int nt = blockIdx.x;            // 0..127
    const int q  = blockIdx.y;            // 0..3 (k quarter)
    const int n0 = nt * 32;

    {
        const int rbase = t >> 2, cg = (t & 3) * 8;
        #pragma unroll
        for (int rep = 0; rep < 4; ++rep) {
            const int r = rbase + rep * 64;
            const float* src = wgt + (size_t)(q * 256 + r) * OUT_DIM + n0 + cg;
            float4 v0 = ((const float4*)src)[0];
            float4 v1 = ((const float4*)src)[1];
            float* d = &tile[r * 33 + cg];
            d[0] = v0.x; d[1] = v0.y; d[2] = v0.z; d[3] = v0.w;
            d[4] = v1.x; d[5] = v1.y; d[6] = v1.z; d[7] = v1.w;
        }
    }
    __syncthreads();

    const int kt2 = q * 4 + w;
    const int n   = l & 31;
    const int kb  = w * 64 + (l >> 5) * 32;
    float s = 0.0f;
    i32x4 lo, hi;
    #pragma unroll
    for (int j4 = 0; j4 < 4; ++j4) {
        float f0 = tile[(kb + j4 * 4 + 0) * 33 + n];
        float f1 = tile[(kb + j4 * 4 + 1) * 33 + n];
        float f2 = tile[(kb + j4 * 4 + 2) * 33 + n];
        float f3 = tile[(kb + j4 * 4 + 3) * 33 + n];
        s += f0*f0 + f1*f1 + f2*f2 + f3*f3;
        lo[j4] = pack4_fp8(f0, f1, f2, f3);
    }
    #pragma unroll
    for (int j4 = 0; j4 < 4; ++j4) {
        float f0 = tile[(kb + 16 + j4 * 4 + 0) * 33 + n];
        float f1 = tile[(kb + 16 + j4 * 4 + 1) * 33 + n];
        float f2 = tile[(kb + 16 + j4 * 4 + 2) * 33 + n];
        float f3 = tile[(kb + 16 + j4 * 4 + 3) * 33 + n];
        s += f0*f0 + f1*f1 + f2*f2 + f3*f3;
        hi[j4] = pack4_fp8(f0, f1, f2, f3);
    }
    unsigned char* pan = Bt + ((size_t)nt * KT2 + kt2) * 2048;
    *(i32x4*)(pan + l * 16)        = lo;
    *(i32x4*)(pan + 1024 + l * 16) = hi;

    s += __shfl_down(s, 32, 64);
    __shared__ float red[4][32];
    if (l < 32) red[w][l] = s;
    __syncthreads();
    if (t < 32) atomicAdd(&wsq[n0 + t], red[0][t] + red[1][t] + red[2][t] + red[3][t]);
}

// ---------------------------------------------------------------------------
// Kernel 3: MX-fp8 GEMM. A: LDS double-buffered DMA (2 x 16 KB -> 3 blocks/CU
// vs round-5's 2). B: DIRECT global->register frag loads (panel layout is
// lane-linear), prefetched one K-iter ahead; grid x=bm fastest so consecutive
// blocks share the same 128 KB B slice (L2-hot). Halves LDS traffic and the
// barrier-coupled staging bytes. 128x128 tile, BK=128, 4 waves x 2x2 frags of
// mfma_scale_f32_32x32x64_f8f6f4 (unit E8M0 scales).
// Epilogue fuses out = xsq[m] + wsq[n] - 2*cross.
// ---------------------------------------------------------------------------
__global__ __launch_bounds__(256) void rbf_gemm_kernel(
    const unsigned char* __restrict__ At,   // [256*KT2][2048]
    const unsigned char* __restrict__ Bt,   // [128*KT2][2048]
    const float* __restrict__ xsq,
    const float* __restrict__ wsq,
    float* __restrict__ out)
{
    __shared__ __align__(16) unsigned char smA[2][16384];   // 8 A panels per buffer

    const int t    = threadIdx.x;
    const int w    = t >> 6;
    const int l    = t & 63;
    const int l32  = l & 31;
    const int half = l >> 5;
    const int bm = blockIdx.x;   // 0..63 (fastest-varying)
    const int bn = blockIdx.y;   // 0..31
    const int waveRow = w >> 1;
    const int waveCol = w & 1;

    f32x16 acc[2][2];
    #pragma unroll
    for (int mi = 0; mi < 2; ++mi)
        #pragma unroll
        for (int ni = 0; ni < 2; ++ni)
            #pragma unroll
            for (int r = 0; r < 16; ++r)
                acc[mi][ni][r] = 0.0f;

    // stage A K-iter kti into buffer buf: wave w stages its row-tile's 2 panels
    auto stageA = [&](int buf, int kti) {
        #pragma unroll
        for (int pp = 0; pp < 2; ++pp) {
            const unsigned char* ga =
                At + ((size_t)(bm * 4 + w) * KT2 + kti * 2 + pp) * 2048;
            unsigned char* ld = smA[buf] + (w * 2 + pp) * 2048;
            async_copy16(ga + l * 16,        ld);
            async_copy16(ga + 1024 + l * 16, ld + 1024);
        }
    };

    // direct global B frag load (lane-linear; hits L2 via bm-major dispatch)
    auto ldB = [&](int ni, int kti, int ks) -> i32x8 {
        const unsigned char* gb =
            Bt + ((size_t)(bn * 4 + waveCol * 2 + ni) * KT2 + kti * 2 + ks) * 2048
               + l * 16;
        i32x4 lo = *(const i32x4*)gb;
        i32x4 hi = *(const i32x4*)(gb + 1024);
        i32x8 r;
        r[0] = lo[0]; r[1] = lo[1]; r[2] = lo[2]; r[3] = lo[3];
        r[4] = hi[0]; r[5] = hi[1]; r[6] = hi[2]; r[7] = hi[3];
        return r;
    };

    auto ldA = [&](const unsigned char* base, int p) -> i32x8 {
        i32x4 lo = *(const i32x4*)(base + p * 2048 + l * 16);
        i32x4 hi = *(const i32x4*)(base + p * 2048 + 1024 + l * 16);
        i32x8 r;
        r[0] = lo[0]; r[1] = lo[1]; r[2] = lo[2]; r[3] = lo[3];
        r[4] = hi[0]; r[5] = hi[1]; r[6] = hi[2]; r[7] = hi[3];
        return r;
    };

    stageA(0, 0);
    i32x8 bcur[2][2];
    #pragma unroll
    for (int ks = 0; ks < 2; ++ks)
        #pragma unroll
        for (int ni = 0; ni < 2; ++ni)
            bcur[ks][ni] = ldB(ni, 0, ks);
    __syncthreads();                       // drain A tile-0 DMAs

    for (int kti = 0; kti < 8; ++kti) {
        if (kti < 7) stageA((kti + 1) & 1, kti + 1);
        const int nk = (kti < 7) ? kti + 1 : 7;   // clamp: last prefetch redundant
        i32x8 bnxt[2][2];
        #pragma unroll
        for (int ks = 0; ks < 2; ++ks)
            #pragma unroll
            for (int ni = 0; ni < 2; ++ni)
                bnxt[ks][ni] = ldB(ni, nk, ks);

        const unsigned char* As = smA[kti & 1];
        #pragma unroll
        for (int ks = 0; ks < 2; ++ks) {
            i32x8 af[2];
            #pragma unroll
            for (int mi = 0; mi < 2; ++mi)
                af[mi] = ldA(As, (waveRow * 2 + mi) * 2 + ks);
            #pragma unroll
            for (int mi = 0; mi < 2; ++mi)
                #pragma unroll
                for (int ni = 0; ni < 2; ++ni)
                    acc[mi][ni] = __builtin_amdgcn_mfma_scale_f32_32x32x64_f8f6f4(
                        af[mi], bcur[ks][ni], acc[mi][ni],
                        0, 0,                 // cbsz=fp8(e4m3), blgp=fp8(e4m3)
                        0, 0x7F7F7F7F,        // A scales = 1.0 (E8M0 127)
                        0, 0x7F7F7F7F);       // B scales = 1.0
        }
        __syncthreads();   // RAW for A tile kti+1, WAR for A buffer reuse
        #pragma unroll
        for (int ks = 0; ks < 2; ++ks)
            #pragma unroll
            for (int ni = 0; ni < 2; ++ni)
                bcur[ks][ni] = bnxt[ks][ni];
    }

    // Epilogue. 32x32 C/D layout: col(n)=lane&31, row(m)=(r&3)+8*(r>>2)+4*(l>>5).
    #pragma unroll
    for (int mi = 0; mi < 2; ++mi) {
        const int mbase = bm * 128 + waveRow * 64 + mi * 32 + 4 * half;
        #pragma unroll
        for (int r2 = 0; r2 < 4; ++r2) {
            #pragma unroll
            for (int r1 = 0; r1 < 4; ++r1) {
                const int m  = mbase + r1 + 8 * r2;
                const float xs = xsq[m];
                #pragma unroll
                for (int ni = 0; ni < 2; ++ni) {
                    const int n = bn * 128 + waveCol * 64 + ni * 32 + l32;
                    out[(size_t)m * OUT_DIM + n] =
                        xs + wsq[n] - 2.0f * acc[mi][ni][r2 * 4 + r1];
                }
            }
        }
    }
}

// ---------------------------------------------------------------------------
extern "C" void kernel_launch(void* const* d_in, const int* in_sizes, int n_in,
                              void* d_out, int out_size, void* d_ws, size_t ws_size,
                              hipStream_t stream)
{
    const float* x   = (const float*)d_in[0];   // (8192, 1024) fp32
    const float* wgt = (const float*)d_in[1];   // (1024, 4096) fp32
    float* out = (float*)d_out;                 // (8192, 4096) fp32
    char*  ws  = (char*)d_ws;

    // workspace: At (8 MB) | Bt (4 MB) | xsq (32 KB) | wsq (16 KB)
    unsigned char* At = (unsigned char*)ws;
    unsigned char* Bt = (unsigned char*)(ws + (size_t)B_DIM * IN_DIM);
    float* xsq = (float*)(ws + (size_t)B_DIM * IN_DIM + (size_t)OUT_DIM * IN_DIM);
    float* wsq = xsq + B_DIM;

    tile_x_kernel<<<B_DIM / 32, 256, 0, stream>>>(x, At, xsq, wsq);
    tile_w_kernel<<<dim3(OUT_DIM / 32, 4), 256, 0, stream>>>(wgt, Bt, wsq);
    rbf_gemm_kernel<<<dim3(B_DIM / 128, OUT_DIM / 128), 256, 0, stream>>>(At, Bt, xsq, wsq, out);
}